// Round 1
// baseline (9.948 us; speedup 1.0000x reference)
//
#include <hip/hip_runtime.h>

// ACF model forward. Key observation: the reference's item-level attention
// applies softmax over a size-1 axis (shape [B,L,1], axis=-1), which is
// identically 1.0. Hence all_a = sum_l Pi[user_pos[b,l], :] and the entire
// component/item attention MLP stack is numerically dead code.
//
// Outputs (flat concat, return order): xui[B], gu[B,F], gi[B,F], pi[B,F].

#define BB   256   // batch
#define LL   32    // positives per user
#define FF   200   // factors

__global__ __launch_bounds__(256) void acf_kernel(
    const int*   __restrict__ user,
    const int*   __restrict__ item,
    const int*   __restrict__ user_pos,
    const float* __restrict__ Gu,
    const float* __restrict__ Gi,
    const float* __restrict__ Pi,
    float* __restrict__ out)   // [xui(B) | gu(B*F) | gi(B*F) | pi(B*F)]
{
    const int b = blockIdx.x;
    const int t = threadIdx.x;

    __shared__ int   s_pos[LL];
    __shared__ float s_red[4];

    // stage the 32 positive indices once per block (broadcast thereafter)
    if (t < LL) s_pos[t] = user_pos[b * LL + t];
    __syncthreads();

    const int u  = user[b];
    const int it = item[b];

    float partial = 0.0f;
    if (t < FF) {
        const float gu = Gu[(size_t)u  * FF + t];
        const float gi = Gi[(size_t)it * FF + t];
        const float pi = Pi[(size_t)it * FF + t];

        float* out_gu = out + BB;
        float* out_gi = out + BB + BB * FF;
        float* out_pi = out + BB + 2 * BB * FF;
        out_gu[b * FF + t] = gu;
        out_gi[b * FF + t] = gi;
        out_pi[b * FF + t] = pi;

        // all_a[f] = sum_l Pi[user_pos[b,l], f]   (softmax over size-1 axis == 1)
        float alla = 0.0f;
        #pragma unroll
        for (int l = 0; l < LL; ++l) {
            alla += Pi[(size_t)s_pos[l] * FF + t];
        }
        partial = (gu + alla) * gi;
    }

    // block reduce: wave64 shuffle then cross-wave via LDS
    #pragma unroll
    for (int off = 32; off > 0; off >>= 1)
        partial += __shfl_down(partial, off, 64);

    const int wave = t >> 6;
    const int lane = t & 63;
    if (lane == 0) s_red[wave] = partial;
    __syncthreads();
    if (t == 0) {
        out[b] = s_red[0] + s_red[1] + s_red[2] + s_red[3];  // xui[b]
    }
}

extern "C" void kernel_launch(void* const* d_in, const int* in_sizes, int n_in,
                              void* d_out, int out_size, void* d_ws, size_t ws_size,
                              hipStream_t stream) {
    const int*   user     = (const int*)  d_in[0];
    const int*   item     = (const int*)  d_in[1];
    const int*   user_pos = (const int*)  d_in[2];
    const float* Gu       = (const float*)d_in[3];
    const float* Gi       = (const float*)d_in[4];
    const float* Pi       = (const float*)d_in[5];
    float* out = (float*)d_out;

    acf_kernel<<<BB, 256, 0, stream>>>(user, item, user_pos, Gu, Gi, Pi, out);
}

// Round 2
// 9.457 us; speedup vs baseline: 1.0519x; 1.0519x over previous
//
#include <hip/hip_runtime.h>

// ACF model forward. The reference's item-level attention applies softmax over
// a size-1 axis ([B,L,1], axis=-1) == 1.0 identically, so
//   all_a = sum_l Pi[user_pos[b,l], :]
// and the entire component/item attention MLP stack is numerically dead code.
//   xui[b] = dot(Gu[user[b]] + all_a, Gi[item[b]])
// Outputs (flat concat): xui[B], gu[B,F], gi[B,F], pi[B,F].
//
// Latency-optimized: one wave per batch row, zero barriers, float4 gathers
// (16 B/lane), __shfl index broadcast instead of LDS.

#define BB   256   // batch
#define LL   32    // positives per user
#define FF   200   // factors
#define NC   50    // float4 chunks per row (200/4)

__global__ __launch_bounds__(64) void acf_kernel(
    const int*   __restrict__ user,
    const int*   __restrict__ item,
    const int*   __restrict__ user_pos,
    const float* __restrict__ Gu,
    const float* __restrict__ Gi,
    const float* __restrict__ Pi,
    float* __restrict__ out)   // [xui(B) | gu(B*F) | gi(B*F) | pi(B*F)]
{
    const int b    = blockIdx.x;
    const int lane = threadIdx.x;   // 0..63, one wave

    const int u  = user[b];
    const int it = item[b];

    // lane l (<32) holds positive index l; broadcast later via shfl
    int myidx = (lane < LL) ? user_pos[b * LL + lane] : 0;

    const float4* Gu4 = (const float4*)Gu;
    const float4* Gi4 = (const float4*)Gi;
    const float4* Pi4 = (const float4*)Pi;

    const bool active = lane < NC;

    float4 gu4 = make_float4(0.f, 0.f, 0.f, 0.f);
    float4 gi4 = gu4, pi4 = gu4;
    if (active) {
        gu4 = Gu4[(size_t)u  * NC + lane];
        gi4 = Gi4[(size_t)it * NC + lane];
        pi4 = Pi4[(size_t)it * NC + lane];
    }

    // broadcast the 32 indices across the wave (register-only, no LDS/barrier)
    int idx[LL];
    #pragma unroll
    for (int l = 0; l < LL; ++l) idx[l] = __shfl(myidx, l, 64);

    // all_a chunk: sum of 32 gathered float4 (independent loads, deep in flight)
    float4 alla = make_float4(0.f, 0.f, 0.f, 0.f);
    #pragma unroll
    for (int l = 0; l < LL; ++l) {
        if (active) {
            float4 v = Pi4[(size_t)idx[l] * NC + lane];
            alla.x += v.x; alla.y += v.y; alla.z += v.z; alla.w += v.w;
        }
    }

    // write gathered rows
    if (active) {
        float4* out_gu = (float4*)(out + BB);
        float4* out_gi = (float4*)(out + BB + BB * FF);
        float4* out_pi = (float4*)(out + BB + 2 * BB * FF);
        out_gu[b * NC + lane] = gu4;
        out_gi[b * NC + lane] = gi4;
        out_pi[b * NC + lane] = pi4;
    }

    // partial dot over this lane's 4 factors
    float partial = 0.f;
    if (active) {
        partial = (gu4.x + alla.x) * gi4.x
                + (gu4.y + alla.y) * gi4.y
                + (gu4.z + alla.z) * gi4.z
                + (gu4.w + alla.w) * gi4.w;
    }

    // wave64 shuffle reduce
    #pragma unroll
    for (int off = 32; off > 0; off >>= 1)
        partial += __shfl_down(partial, off, 64);

    if (lane == 0) out[b] = partial;   // xui[b]
}

extern "C" void kernel_launch(void* const* d_in, const int* in_sizes, int n_in,
                              void* d_out, int out_size, void* d_ws, size_t ws_size,
                              hipStream_t stream) {
    const int*   user     = (const int*)  d_in[0];
    const int*   item     = (const int*)  d_in[1];
    const int*   user_pos = (const int*)  d_in[2];
    const float* Gu       = (const float*)d_in[3];
    const float* Gi       = (const float*)d_in[4];
    const float* Pi       = (const float*)d_in[5];
    float* out = (float*)d_out;

    acf_kernel<<<BB, 64, 0, stream>>>(user, item, user_pos, Gu, Gi, Pi, out);
}